// Round 5
// baseline (289.748 us; speedup 1.0000x reference)
//
#include <hip/hip_runtime.h>

#define NQ 1764
#define NQP 1792             // keys padded to 28*64, zero-filled by prep
#define DIM 256
#define KT 32                // keys per attn tile
#define NTILES 56
#define QBLK 112             // queries stored per block (16 blocks/batch)

// ---- attn LDS map (halfword units), double-buffered tiles ----
#define RM_SZ (KT * DIM)                  // 8192 hw: [32 keys][256 d]
#define TR_SZ (DIM * KT)                  // 8192 hw: [256 d][32 keys]
#define BUF_SZ (RM_SZ + TR_SZ)            // 16384
#define P_OFF (2 * BUF_SZ)                // 32768
#define P_STRIDE 40
#define SM_TOTAL (P_OFF + 4 * 32 * P_STRIDE)   // 37888 hw = 75776 B -> 2 blocks/CU

// ---- workspace map ----
#define WS_MRM_HW ((size_t)16 * NQP * DIM)     // 7,340,032 hw
#define WS_MTR_HW WS_MRM_HW
#define WS_PO_F   ((size_t)2 * 16 * NQP * DIM) // 14,680,064 f
#define WS_PL_F   ((size_t)2 * 16 * NQP)
#define WS_SPLIT_BYTES (2 * 2 * WS_MRM_HW + 4 * (WS_PO_F + WS_PL_F))  // 88,309,760

typedef __attribute__((ext_vector_type(4))) short short4v;
typedef __attribute__((ext_vector_type(8))) short short8v;
typedef __attribute__((ext_vector_type(4))) float float4v;

static __device__ __forceinline__ ushort f2bf(float f) {
  union { float f; unsigned u; } v; v.f = f;
  return (ushort)((v.u + 0x7FFFu + ((v.u >> 16) & 1u)) >> 16);  // RNE
}

static __device__ __forceinline__ void dma16(const void* g, void* l) {
  __builtin_amdgcn_global_load_lds(
      (__attribute__((address_space(1))) void*)(void*)g,
      (__attribute__((address_space(3))) void*)l, 16, 0, 0);
}

// ============ prep: m -> bf16 row-major [16][1792][256] + transposed [16][256][1792] ============
__global__ __launch_bounds__(512)
void prep_m(const float* __restrict__ mg, ushort* __restrict__ mrm,
            ushort* __restrict__ mtr)
{
  __shared__ float smf[64 * 260];
  const int tid = threadIdx.x;
  const int b   = blockIdx.x & 15;
  const int kt  = blockIdx.x >> 4;      // 0..27, 64-key chunks
  const int k0  = kt * 64;
  const float* mb = mg + (size_t)b * NQ * DIM;

  #pragma unroll
  for (int i = 0; i < 8; ++i) {
    const int idx = i * 512 + tid;      // 4096 float4 slots
    const int row = idx >> 6;
    const int c4  = (idx & 63) * 4;
    const int gk  = k0 + row;
    float4v v = (gk < NQ) ? *(const float4v*)(mb + (size_t)gk * DIM + c4)
                          : (float4v){0.f, 0.f, 0.f, 0.f};
    *(float4v*)&smf[row * 260 + c4] = v;
    union { short4v v4; short e[4]; } h;
    #pragma unroll
    for (int j = 0; j < 4; ++j) h.e[j] = (short)f2bf(v[j]);
    *(short4v*)(mrm + ((size_t)b * NQP + k0 + row) * DIM + c4) = h.v4;
  }
  __syncthreads();

  const int d  = tid >> 1;              // 0..255
  const int hf = tid & 1;               // key-half of the 64
  ushort* dst = mtr + ((size_t)b * DIM + d) * NQP + k0;
  #pragma unroll
  for (int kc = 0; kc < 4; ++kc) {
    const int chunk = hf * 4 + kc;      // 0..7 -> keys chunk*8..+8
    union { short8v v; short e[8]; } u;
    #pragma unroll
    for (int j = 0; j < 8; ++j)
      u.e[j] = (short)f2bf(smf[(chunk * 8 + j) * 260 + d]);
    *(short8v*)(dst + chunk * 8) = u.v;
  }
}

// ============================ attention ============================
// Block = 4 waves, 32 q/wave (two 16-row subtiles). nkh=2: grid 512, block kh
// processes 28 of 56 key-tiles, stores partial (O,l) to ws; combine finishes.
// nkh=1: grid 256, full K range, final output written directly.
// w_lin cancels in softmax; no max-subtract needed (|s| small).

static __device__ __forceinline__ void stage_tile(const ushort* mrb, const ushort* mtb,
                                                  ushort* smb, int k0, int w, int lane)
{
  // RM [k][cs] <- global d-chunk cs^(k&7)
  #pragma unroll
  for (int j = 0; j < 4; ++j) {
    const int L  = (w * 4 + j) * 64 + lane;   // 0..1023
    const int k  = L >> 5;
    const int cs = L & 31;
    const int gc = cs ^ (k & 7);
    dma16(mrb + (size_t)(k0 + k) * DIM + gc * 8, smb + (w * 4 + j) * 512);
  }
  // TR [d][t] <- global key-chunk t^((d>>1)&3)  (conflict-free PV reads)
  #pragma unroll
  for (int j = 0; j < 4; ++j) {
    const int L = (w * 4 + j) * 64 + lane;
    const int d = L >> 2;
    const int t = L & 3;
    const int kc = t ^ ((d >> 1) & 3);
    dma16(mtb + (size_t)d * NQP + k0 + kc * 8, smb + RM_SZ + (w * 4 + j) * 512);
  }
}

__global__ __launch_bounds__(256, 2)
void attn_fused(const float* __restrict__ x, const ushort* __restrict__ mrm,
                const ushort* __restrict__ mtr, const int* __restrict__ maskg,
                const float* __restrict__ scale, float* __restrict__ out,
                float* __restrict__ pO, float* __restrict__ pl, int nkh)
{
  __shared__ ushort sm[SM_TOTAL];
  const int tid  = threadIdx.x;
  const int w    = tid >> 6;
  const int lane = tid & 63;
  const int l15  = lane & 15;
  const int quad = lane >> 4;
  const int l7   = l15 & 7;

  const int b      = blockIdx.x & 15;
  const int qblk   = (blockIdx.x >> 4) & 15;
  const int kh     = blockIdx.x >> 8;      // 0 when nkh==1
  const int qbase0 = qblk * QBLK;
  const int qbase  = qbase0 + w * 32;
  const int ntiles = NTILES / nkh;
  const int ktbase = kh * ntiles;

  const float*  xb  = x + (size_t)b * NQ * DIM;
  const ushort* mrb = mrm + (size_t)b * NQP * DIM;
  const ushort* mtb = mtr + (size_t)b * DIM * NQP;
  const int*    mkb = maskg + (size_t)b * NQ;
  float*        ob  = out + (size_t)b * NQ * (2 * DIM);

  // ---- resident Q fragments: Q = x*scale, bf16, A-layout ----
  short8v qa0[8], qa1[8];
  {
    int q0 = qbase + l15;      q0 = q0 < NQ ? q0 : NQ - 1;
    int q1 = qbase + 16 + l15; q1 = q1 < NQ ? q1 : NQ - 1;
    const float* xr0 = xb + (size_t)q0 * DIM;
    const float* xr1 = xb + (size_t)q1 * DIM;
    #pragma unroll
    for (int kk = 0; kk < 8; ++kk) {
      const int dof = kk * 32 + quad * 8;
      const float4v sa = *(const float4v*)(scale + dof);
      const float4v sb = *(const float4v*)(scale + dof + 4);
      const float4v a0 = *(const float4v*)(xr0 + dof);
      const float4v a1 = *(const float4v*)(xr0 + dof + 4);
      const float4v b0 = *(const float4v*)(xr1 + dof);
      const float4v b1 = *(const float4v*)(xr1 + dof + 4);
      union { short8v v; short e[8]; } u0, u1;
      #pragma unroll
      for (int j = 0; j < 4; ++j) {
        u0.e[j]     = (short)f2bf(a0[j] * sa[j]);
        u0.e[j + 4] = (short)f2bf(a1[j] * sb[j]);
        u1.e[j]     = (short)f2bf(b0[j] * sa[j]);
        u1.e[j + 4] = (short)f2bf(b1[j] * sb[j]);
      }
      qa0[kk] = u0.v;
      qa1[kk] = u1.v;
    }
  }

  float4v o0[16], o1[16];
  #pragma unroll
  for (int dt = 0; dt < 16; ++dt) {
    o0[dt] = (float4v){0.f, 0.f, 0.f, 0.f};
    o1[dt] = (float4v){0.f, 0.f, 0.f, 0.f};
  }
  float l0[4] = {0.f, 0.f, 0.f, 0.f};
  float l1[4] = {0.f, 0.f, 0.f, 0.f};

  stage_tile(mrb, mtb, sm, ktbase * KT, w, lane);   // prefetch first tile

  #pragma unroll 1
  for (int t = 0; t < ntiles; ++t) {
    __syncthreads();   // drains DMA (vmcnt 0) + syncs buffer reuse
    if (t + 1 < ntiles)
      stage_tile(mrb, mtb, sm + ((t + 1) & 1) * BUF_SZ, (ktbase + t + 1) * KT, w, lane);

    const int k0 = (ktbase + t) * KT;
    const ushort* rmp = sm + (t & 1) * BUF_SZ;
    const ushort* trp = rmp + RM_SZ;

    bool mv[2];
    #pragma unroll
    for (int ks = 0; ks < 2; ++ks) {
      const int key = k0 + ks * 16 + l15;
      mv[ks] = (key < NQ) && (mkb[key < NQ ? key : 0] != 0);
    }

    // ---- S = Q·m^T: 4 independent MFMA chains (qs x ks) ----
    float4v s00 = {0.f,0.f,0.f,0.f}, s10 = {0.f,0.f,0.f,0.f};
    float4v s01 = {0.f,0.f,0.f,0.f}, s11 = {0.f,0.f,0.f,0.f};
    {
      const ushort* row0 = rmp + l15 * DIM;
      const ushort* row1 = rmp + (16 + l15) * DIM;
      #pragma unroll
      for (int kk = 0; kk < 8; ++kk) {
        const int coff = (((kk * 4 + quad) ^ l7) * 8);
        const short8v bv0 = *(const short8v*)(row0 + coff);
        const short8v bv1 = *(const short8v*)(row1 + coff);
        s00 = __builtin_amdgcn_mfma_f32_16x16x32_bf16(qa0[kk], bv0, s00, 0, 0, 0);
        s10 = __builtin_amdgcn_mfma_f32_16x16x32_bf16(qa1[kk], bv0, s10, 0, 0, 0);
        s01 = __builtin_amdgcn_mfma_f32_16x16x32_bf16(qa0[kk], bv1, s01, 0, 0, 0);
        s11 = __builtin_amdgcn_mfma_f32_16x16x32_bf16(qa1[kk], bv1, s11, 0, 0, 0);
      }
    }
    #pragma unroll
    for (int r = 0; r < 4; ++r) {
      const float p00 = mv[0] ? exp2f(s00[r] * 1.44269504089f) : 0.0f;
      const float p01 = mv[1] ? exp2f(s01[r] * 1.44269504089f) : 0.0f;
      const float p10 = mv[0] ? exp2f(s10[r] * 1.44269504089f) : 0.0f;
      const float p11 = mv[1] ? exp2f(s11[r] * 1.44269504089f) : 0.0f;
      l0[r] += p00 + p01;
      l1[r] += p10 + p11;
      const int row0 = w * 32 + quad * 4 + r;
      const int row1 = row0 + 16;
      sm[P_OFF + row0 * P_STRIDE + l15]      = f2bf(p00);
      sm[P_OFF + row0 * P_STRIDE + 16 + l15] = f2bf(p01);
      sm[P_OFF + row1 * P_STRIDE + l15]      = f2bf(p10);
      sm[P_OFF + row1 * P_STRIDE + 16 + l15] = f2bf(p11);
    }

    // ---- O += P·m ----
    {
      const short8v pa0 = *(const short8v*)&sm[P_OFF + (w * 32 + l15) * P_STRIDE + quad * 8];
      const short8v pa1 = *(const short8v*)&sm[P_OFF + (w * 32 + 16 + l15) * P_STRIDE + quad * 8];
      #pragma unroll
      for (int dt = 0; dt < 16; ++dt) {
        const int d = dt * 16 + l15;
        const short8v bv = *(const short8v*)(trp + d * KT + ((quad ^ ((d >> 1) & 3)) * 8));
        o0[dt] = __builtin_amdgcn_mfma_f32_16x16x32_bf16(pa0, bv, o0[dt], 0, 0, 0);
        o1[dt] = __builtin_amdgcn_mfma_f32_16x16x32_bf16(pa1, bv, o1[dt], 0, 0, 0);
      }
    }
  }

  // ---- reduce l over the 16 lanes of each quad ----
  float ls0[4], ls1[4];
  #pragma unroll
  for (int r = 0; r < 4; ++r) {
    float a = l0[r], c = l1[r];
    a += __shfl_xor(a, 1); a += __shfl_xor(a, 2);
    a += __shfl_xor(a, 4); a += __shfl_xor(a, 8);
    c += __shfl_xor(c, 1); c += __shfl_xor(c, 2);
    c += __shfl_xor(c, 4); c += __shfl_xor(c, 8);
    ls0[r] = a;
    ls1[r] = c;
  }

  __syncthreads();   // tiles + P dead; reuse LDS for O transpose
  float* ew = (float*)sm + w * 4160;   // per-wave [16 q][260] fp32

  if (nkh == 1) {
    // final epilogue: divide, store out, copy x
    #pragma unroll
    for (int qs = 0; qs < 2; ++qs) {
      #pragma unroll
      for (int dt = 0; dt < 16; ++dt)
        #pragma unroll
        for (int r = 0; r < 4; ++r)
          ew[(quad * 4 + r) * 260 + dt * 16 + l15] =
              qs ? (o1[dt][r] / ls1[r]) : (o0[dt][r] / ls0[r]);
      #pragma unroll
      for (int i = 0; i < 4; ++i)
        #pragma unroll
        for (int jj = 0; jj < 4; ++jj) {
          const int row = i * 4 + quad;
          const int lq  = w * 32 + qs * 16 + row;
          const int q   = qbase0 + lq;
          if (lq < QBLK && q < NQ) {
            const float4v v = *(const float4v*)&ew[row * 260 + (jj * 16 + l15) * 4];
            *(float4v*)(ob + (size_t)q * (2 * DIM) + DIM + (jj * 16 + l15) * 4) = v;
          }
        }
    }
    #pragma unroll
    for (int i = 0; i < 28; ++i) {
      const int idx = i * 256 + tid;
      const int row = idx >> 6;
      const int c4  = (idx & 63) * 4;
      const int q   = qbase0 + row;
      if (q < NQ) {
        const float4v v = *(const float4v*)(xb + (size_t)q * DIM + c4);
        *(float4v*)(ob + (size_t)q * (2 * DIM) + c4) = v;
      }
    }
  } else {
    // partial epilogue: store raw O (transposed for coalescing) + l
    float* po_b = pO + ((size_t)kh * 16 + b) * NQP * DIM;
    float* pl_b = pl + ((size_t)kh * 16 + b) * NQP;
    #pragma unroll
    for (int qs = 0; qs < 2; ++qs) {
      #pragma unroll
      for (int dt = 0; dt < 16; ++dt)
        #pragma unroll
        for (int r = 0; r < 4; ++r)
          ew[(quad * 4 + r) * 260 + dt * 16 + l15] = qs ? o1[dt][r] : o0[dt][r];
      #pragma unroll
      for (int i = 0; i < 4; ++i)
        #pragma unroll
        for (int jj = 0; jj < 4; ++jj) {
          const int row = i * 4 + quad;
          const int lq  = w * 32 + qs * 16 + row;
          if (lq < QBLK) {
            const float4v v = *(const float4v*)&ew[row * 260 + (jj * 16 + l15) * 4];
            *(float4v*)(po_b + (size_t)(qbase0 + lq) * DIM + (jj * 16 + l15) * 4) = v;
          }
        }
      if (l15 == 0)
        #pragma unroll
        for (int r = 0; r < 4; ++r) {
          const int lq = w * 32 + qs * 16 + quad * 4 + r;
          if (lq < QBLK) pl_b[qbase0 + lq] = qs ? ls1[r] : ls0[r];
        }
    }
  }
}

// ============ combine: out = [x | (O0+O1)/(l0+l1)] ============
__global__ __launch_bounds__(256)
void combine(const float* __restrict__ x, const float* __restrict__ pO,
             const float* __restrict__ pl, float* __restrict__ out)
{
  const int idx = blockIdx.x * 256 + threadIdx.x;   // 3,612,672 total
  const int row = idx >> 7;            // b*1764 + q
  const int c   = idx & 127;
  if (c < 64) {
    const float4v v = *(const float4v*)(x + (size_t)row * DIM + c * 4);
    *(float4v*)(out + (size_t)row * (2 * DIM) + c * 4) = v;
  } else {
    const int b = row / NQ;
    const int q = row - b * NQ;
    const int d4 = c - 64;
    const size_t half = (size_t)16 * NQP * DIM;
    const size_t base = ((size_t)b * NQP + q) * DIM + d4 * 4;
    const float4v a  = *(const float4v*)(pO + base);
    const float4v bb = *(const float4v*)(pO + base + half);
    const float l = pl[(size_t)b * NQP + q] + pl[(size_t)16 * NQP + b * NQP + q];
    const float inv = 1.0f / l;
    float4v r;
    #pragma unroll
    for (int j = 0; j < 4; ++j) r[j] = (a[j] + bb[j]) * inv;
    *(float4v*)(out + (size_t)row * (2 * DIM) + DIM + d4 * 4) = r;
  }
}

extern "C" void kernel_launch(void* const* d_in, const int* in_sizes, int n_in,
                              void* d_out, int out_size, void* d_ws, size_t ws_size,
                              hipStream_t stream) {
  const float* x     = (const float*)d_in[0];
  const float* mem   = (const float*)d_in[1];
  const int*   mask  = (const int*)d_in[2];
  // d_in[3] = w_lin: cancels in softmax (per-row constant) — unused
  const float* scale = (const float*)d_in[4];
  float* out = (float*)d_out;

  ushort* wsm = (ushort*)d_ws;
  ushort* wst = wsm + WS_MRM_HW;
  float*  pO  = (float*)(wst + WS_MTR_HW);
  float*  pl  = pO + WS_PO_F;

  prep_m<<<dim3(448), dim3(512), 0, stream>>>(mem, wsm, wst);
  if (ws_size >= WS_SPLIT_BYTES) {
    attn_fused<<<dim3(512), dim3(256), 0, stream>>>(x, wsm, wst, mask, scale,
                                                    out, pO, pl, 2);
    combine<<<dim3(14112), dim3(256), 0, stream>>>(x, pO, pl, out);
  } else {
    attn_fused<<<dim3(256), dim3(256), 0, stream>>>(x, wsm, wst, mask, scale,
                                                    out, nullptr, nullptr, 1);
  }
}